// Round 6
// baseline (4592.883 us; speedup 1.0000x reference)
//
#include <hip/hip_runtime.h>
#include <hip/hip_bf16.h>
#include <math.h>

// Problem constants
#define NB    1024      // batch rows == scan steps
#define SEQ   600
#define EDIM  300
#define HDIM  256
#define DIN   903       // 3*E + 3
#define GDIM  1024      // 4*H
#define SENT  0xFFFFFFFFu
#define L2E   1.4426950408889634f

// ---------------------------------------------------------------------------
// Kernel 1: conv — per row: 3 segment means of gathered embeddings + 3 cosines
// ---------------------------------------------------------------------------
__global__ __launch_bounds__(256) void conv_kernel(const int* __restrict__ x,
                                                   const float* __restrict__ emb,
                                                   float* __restrict__ X) {
    const int row = blockIdx.x;
    const int tid = threadIdx.x;
    const int* xr = x + (size_t)row * SEQ;

    __shared__ float seg[3][EDIM];
    __shared__ float scnt[3];
    __shared__ float reds[6];
    __shared__ float coss[3];

    if (tid < 6) reds[tid] = 0.f;
    if (tid < 3) scnt[tid] = 0.f;
    __syncthreads();

    {
        int c0 = 0, c1 = 0, c2 = 0;
        for (int t = tid; t < 200; t += 256) {
            c0 += (xr[t]       != 0);
            c1 += (xr[200 + t] != 0);
            c2 += (xr[400 + t] != 0);
        }
        float f0 = (float)c0, f1 = (float)c1, f2 = (float)c2;
        #pragma unroll
        for (int m = 1; m < 64; m <<= 1) {
            f0 += __shfl_xor(f0, m);
            f1 += __shfl_xor(f1, m);
            f2 += __shfl_xor(f2, m);
        }
        if ((tid & 63) == 0) {
            atomicAdd(&scnt[0], f0);
            atomicAdd(&scnt[1], f1);
            atomicAdd(&scnt[2], f2);
        }
    }
    __syncthreads();

    const float inv0 = 1.f / scnt[0], inv1 = 1.f / scnt[1], inv2 = 1.f / scnt[2];

    for (int d = tid; d < EDIM; d += 256) {
        float a0 = 0.f, a1 = 0.f, a2 = 0.f;
        for (int t = 0; t < 200; t++) {
            a0 += emb[(size_t)xr[t]       * EDIM + d];
            a1 += emb[(size_t)xr[200 + t] * EDIM + d];
            a2 += emb[(size_t)xr[400 + t] * EDIM + d];
        }
        seg[0][d] = a0 * inv0;
        seg[1][d] = a1 * inv1;
        seg[2][d] = a2 * inv2;
    }
    __syncthreads();

    {
        float p0 = 0, p1 = 0, p2 = 0, p3 = 0, p4 = 0, p5 = 0;
        for (int d = tid; d < EDIM; d += 256) {
            float a = seg[0][d], b = seg[1][d], c = seg[2][d];
            p0 += a * a; p1 += b * b; p2 += c * c;
            p3 += a * b; p4 += b * c; p5 += a * c;
        }
        #pragma unroll
        for (int m = 1; m < 64; m <<= 1) {
            p0 += __shfl_xor(p0, m); p1 += __shfl_xor(p1, m);
            p2 += __shfl_xor(p2, m); p3 += __shfl_xor(p3, m);
            p4 += __shfl_xor(p4, m); p5 += __shfl_xor(p5, m);
        }
        if ((tid & 63) == 0) {
            atomicAdd(&reds[0], p0); atomicAdd(&reds[1], p1);
            atomicAdd(&reds[2], p2); atomicAdd(&reds[3], p3);
            atomicAdd(&reds[4], p4); atomicAdd(&reds[5], p5);
        }
    }
    __syncthreads();
    if (tid == 0) {
        float nt = fmaxf(sqrtf(reds[0]), 1e-8f);
        float nu = fmaxf(sqrtf(reds[1]), 1e-8f);
        float nj = fmaxf(sqrtf(reds[2]), 1e-8f);
        coss[0] = reds[3] / (nt * nu);
        coss[1] = reds[4] / (nu * nj);
        coss[2] = reds[5] / (nt * nj);
    }
    __syncthreads();

    float* Xr = X + (size_t)row * DIN;
    for (int col = tid; col < DIN; col += 256) {
        float v;
        if      (col < 300)  v = seg[0][col];
        else if (col == 300) v = coss[0];
        else if (col < 601)  v = seg[1][col - 301];
        else if (col == 601) v = coss[1];
        else if (col < 902)  v = seg[2][col - 602];
        else                 v = coss[2];
        Xr[col] = v;
    }
}

// ---------------------------------------------------------------------------
// Kernel 2: GEMM  C[1024][1024] = A[1024][K] * B[1024][K]^T + bias1 + bias2
// ---------------------------------------------------------------------------
__global__ __launch_bounds__(256) void gemm_bias(const float* __restrict__ A,
                                                 const float* __restrict__ Bm,
                                                 const float* __restrict__ bias1,
                                                 const float* __restrict__ bias2,
                                                 float* __restrict__ C, int K) {
    __shared__ float As[16][68];
    __shared__ float Bs[16][68];
    const int tid = threadIdx.x;
    const int tx = tid & 15, ty = tid >> 4;
    const int m0 = blockIdx.y * 64, n0 = blockIdx.x * 64;

    float acc[4][4] = {};
    for (int k0 = 0; k0 < K; k0 += 16) {
        #pragma unroll
        for (int i = 0; i < 4; i++) {
            int e  = tid + i * 256;
            int rr = e >> 4, kk = e & 15;
            int k  = k0 + kk;
            As[kk][rr] = (k < K) ? A[(size_t)(m0 + rr) * K + k] : 0.f;
            Bs[kk][rr] = (k < K) ? Bm[(size_t)(n0 + rr) * K + k] : 0.f;
        }
        __syncthreads();
        #pragma unroll
        for (int kk = 0; kk < 16; kk++) {
            float a[4], b[4];
            #pragma unroll
            for (int i = 0; i < 4; i++) { a[i] = As[kk][ty * 4 + i]; b[i] = Bs[kk][tx * 4 + i]; }
            #pragma unroll
            for (int i = 0; i < 4; i++)
                #pragma unroll
                for (int j = 0; j < 4; j++)
                    acc[i][j] += a[i] * b[j];
        }
        __syncthreads();
    }
    #pragma unroll
    for (int i = 0; i < 4; i++) {
        int m = m0 + ty * 4 + i;
        #pragma unroll
        for (int j = 0; j < 4; j++) {
            int n = n0 + tx * 4 + j;
            C[(size_t)m * GDIM + n] = acc[i][j] + bias1[n] + bias2[n];
        }
    }
}

// ---------------------------------------------------------------------------
// Fast device math
// ---------------------------------------------------------------------------
__device__ __forceinline__ float fsig(float x) {
    return __builtin_amdgcn_rcpf(1.f + __builtin_amdgcn_exp2f(-L2E * x));
}
__device__ __forceinline__ float ftanh(float x) {
    return 2.f * __builtin_amdgcn_rcpf(1.f + __builtin_amdgcn_exp2f(-2.f * L2E * x)) - 1.f;
}
__device__ __forceinline__ unsigned ald(const unsigned* p) {
    return __hip_atomic_load(p, __ATOMIC_RELAXED, __HIP_MEMORY_SCOPE_AGENT);
}
__device__ __forceinline__ void ast(float* p, float v) {
    __hip_atomic_store((unsigned*)p, __float_as_uint(v),
                       __ATOMIC_RELAXED, __HIP_MEMORY_SCOPE_AGENT);
}
__device__ __forceinline__ float4 poll4(const unsigned* p) {
    unsigned a = SENT, b = SENT, c = SENT, d = SENT;
    int gd = 0;
    do {
        if (a == SENT) a = ald(p + 0);
        if (b == SENT) b = ald(p + 1);
        if (c == SENT) c = ald(p + 2);
        if (d == SENT) d = ald(p + 3);
    } while (((a == SENT) | (b == SENT) | (c == SENT) | (d == SENT)) && ++gd < (1 << 20));
    return make_float4(__uint_as_float(a), __uint_as_float(b),
                       __uint_as_float(c), __uint_as_float(d));
}

// ---------------------------------------------------------------------------
// Kernel 3: fused 2-layer LSTM, weights in LDS (immune to regalloc demotion).
// 24 WGs x 640 threads (10 waves):
//   blk 0..7   = layer 1: owns h1 elems [blk*32, +32), 128 gate rows;
//                Whh0 slice in LDS (128 rows x 260f = 130 KB).
//   blk 8..23  = layer 2: u=blk-8 owns h2 elems [u*16, +16), 64 gate rows;
//                Whh1 + Wih1 slices in LDS (2 x 64 x 260f = 130 KB).
// LDS weight layout: physical row p = elemIdx*4 + gate, padded to 65 float4
// -> all weight/h reads <=2-way bank aliasing (free).
// Waves 0..7 compute; wave 8 = h poller; wave 9 = x poller (L2 only).
// Exchange: write-once sentinel rows ys[t][256] (agent scope). Pollers stage
// into double-buffered LDS hbuf/xbuf + flag release. Lap-safety: poller
// finishing row t-1 implies ALL WGs completed step t-1 (their stores are the
// row), so buffer t&1 (last read at step t-2) is free to overwrite.
// Compute mapping L1 (wave v): lane = chunk(2b)<<4 | (gate(2b)<<2 | jj(2b));
// elem = blk*32 + v*4 + jj; 16 f4 MACs/lane; butterfly over chunk bits
// (xor 16,32); gates collected intra-wave by shuffle; lanes 0..3 hold c,
// update state, store h. L2 analogous with 8 chunks of 32 dims (xor 8,16,32).
// ---------------------------------------------------------------------------
__global__ __launch_bounds__(640) void lstm_fused(
    const float* __restrict__ G1,
    const float* __restrict__ Whh0,
    const float* __restrict__ Wih1,
    const float* __restrict__ Whh1,
    const float* __restrict__ b_ih1,
    const float* __restrict__ b_hh1,
    const float* __restrict__ h0,
    const float* __restrict__ c0,
    float* ys1, float* ys2, float* out)
{
    const int  blk   = blockIdx.x;
    const bool isL2  = blk >= 8;
    const int  layer = isL2 ? 1 : 0;
    const int  tid   = threadIdx.x;
    const int  wv    = tid >> 6;
    const int  lane  = tid & 63;

    __shared__ __align__(16) float4 wlds[8320];     // 130 KB weight slice
    __shared__ __align__(16) float4 hbuf[2][64];
    __shared__ __align__(16) float4 xbuf[2][64];
    __shared__ int hflag;
    __shared__ int xflag;

    if (tid == 0) { hflag = 0; xflag = 0; }

    // ---- stage weights into LDS (once) ----
    if (!isL2) {
        const int w = blk;
        for (int idx = tid; idx < 128 * 64; idx += 640) {
            int p = idx >> 6, k4 = idx & 63;
            int eIdx = p >> 2, g = p & 3;
            int grow = g * 256 + w * 32 + eIdx;
            wlds[p * 65 + k4] = ((const float4*)Whh0)[(size_t)grow * 64 + k4];
        }
    } else {
        const int u = blk - 8;
        for (int idx = tid; idx < 64 * 64; idx += 640) {
            int p = idx >> 6, k4 = idx & 63;
            int eIdx = p >> 2, g = p & 3;
            int grow = g * 256 + u * 16 + eIdx;
            wlds[p * 65 + k4]        = ((const float4*)Whh1)[(size_t)grow * 64 + k4];
            wlds[4160 + p * 65 + k4] = ((const float4*)Wih1)[(size_t)grow * 64 + k4];
        }
    }
    __syncthreads();   // weights + flags ready (only barrier in kernel)

    float* ysL = isL2 ? ys2 : ys1;

    // ---------------- wave 8: h poller ----------------
    if (wv == 8) {
        for (int t = 0; t < NB; t++) {
            float4 hv;
            if (t == 0) hv = ((const float4*)(h0 + layer * HDIM))[lane];
            else        hv = poll4((const unsigned*)&ysL[(size_t)(t - 1) * HDIM + 4 * lane]);
            hbuf[t & 1][lane] = hv;
            __hip_atomic_store(&hflag, t + 1, __ATOMIC_RELEASE,
                               __HIP_MEMORY_SCOPE_WORKGROUP);
        }
        return;
    }
    // ---------------- wave 9: x poller (L2 only) ----------------
    if (wv == 9) {
        if (isL2) {
            for (int t = 0; t < NB; t++) {
                float4 xv = poll4((const unsigned*)&ys1[(size_t)t * HDIM + 4 * lane]);
                if (t >= 2) {   // lap-safety gate before LDS overwrite
                    int gd = 0;
                    while (__hip_atomic_load(&hflag, __ATOMIC_ACQUIRE,
                                             __HIP_MEMORY_SCOPE_WORKGROUP) < t) {
                        if (++gd > (1 << 20)) break;
                    }
                }
                xbuf[t & 1][lane] = xv;
                __hip_atomic_store(&xflag, t + 1, __ATOMIC_RELEASE,
                                   __HIP_MEMORY_SCOPE_WORKGROUP);
            }
        }
        return;
    }

    // ---------------- compute waves (wv 0..7) ----------------
    const int v = wv;

    if (!isL2) {
        // -------- layer 1 --------
        const int c     = lane >> 4;          // chunk 0..3 (64 dims)
        const int rowid = lane & 15;
        const int g     = rowid >> 2;
        const int jj    = rowid & 3;
        const int eIdx  = v * 4 + jj;
        const int elem  = blk * 32 + eIdx;
        const int grow  = g * 256 + elem;
        const int wbase = (eIdx * 4 + g) * 65 + c * 16;
        float cst = c0[elem];                 // meaningful at lanes 0..3

        for (int t = 0; t < NB; t++) {
            float gval = G1[(size_t)t * GDIM + grow];   // issue before spin

            {   int gd = 0;
                while (__hip_atomic_load(&hflag, __ATOMIC_ACQUIRE,
                                         __HIP_MEMORY_SCOPE_WORKGROUP) < t + 1) {
                    if (++gd > (1 << 20)) break;
                }
            }
            const float4* hb = &hbuf[t & 1][0];

            float acc = 0.f;
            #pragma unroll
            for (int k4 = 0; k4 < 16; k4++) {
                float4 w4 = wlds[wbase + k4];
                float4 hv = hb[c * 16 + k4];
                acc += w4.x * hv.x + w4.y * hv.y + w4.z * hv.z + w4.w * hv.w;
            }
            acc += __shfl_xor(acc, 16);
            acc += __shfl_xor(acc, 32);
            float gs = acc + gval;
            float nl = (g == 2) ? ftanh(gs) : fsig(gs);

            float fv = __shfl(nl, 4 + jj, 64);
            float gv = __shfl(nl, 8 + jj, 64);
            float ov = __shfl(nl, 12 + jj, 64);

            if (lane < 4) {                   // elem lanes: nl == i-gate
                cst = fv * cst + nl * gv;
                float h = ov * ftanh(cst);
                ast(&ys1[(size_t)t * HDIM + elem], h);
                if (t == NB - 1) {
                    out[1024 + elem] = h;     // hn L0
                    out[1536 + elem] = cst;   // cn L0
                }
            }
        }
    } else {
        // -------- layer 2 --------
        const int u     = blk - 8;
        const int c3    = lane >> 3;          // chunk 0..7 (32 dims)
        const int rowid = lane & 7;
        const int g     = rowid >> 1;
        const int jj    = rowid & 1;
        const int eIdx  = v * 2 + jj;
        const int elem  = u * 16 + eIdx;
        const int grow  = g * 256 + elem;
        const int whb   = (eIdx * 4 + g) * 65 + c3 * 8;
        const int wib   = 4160 + whb;
        const float bs  = b_ih1[grow] + b_hh1[grow];
        float cst = c0[HDIM + elem];          // meaningful at lanes 0..1

        for (int t = 0; t < NB; t++) {
            {   int gd = 0;
                while (__hip_atomic_load(&hflag, __ATOMIC_ACQUIRE,
                                         __HIP_MEMORY_SCOPE_WORKGROUP) < t + 1) {
                    if (++gd > (1 << 20)) break;
                }
                gd = 0;
                while (__hip_atomic_load(&xflag, __ATOMIC_ACQUIRE,
                                         __HIP_MEMORY_SCOPE_WORKGROUP) < t + 1) {
                    if (++gd > (1 << 20)) break;
                }
            }
            const float4* hb = &hbuf[t & 1][0];
            const float4* xb = &xbuf[t & 1][0];

            float acc = 0.f;
            #pragma unroll
            for (int k4 = 0; k4 < 8; k4++) {
                float4 w4 = wlds[whb + k4];
                float4 hv = hb[c3 * 8 + k4];
                acc += w4.x * hv.x + w4.y * hv.y + w4.z * hv.z + w4.w * hv.w;
            }
            #pragma unroll
            for (int k4 = 0; k4 < 8; k4++) {
                float4 w4 = wlds[wib + k4];
                float4 xv = xb[c3 * 8 + k4];
                acc += w4.x * xv.x + w4.y * xv.y + w4.z * xv.z + w4.w * xv.w;
            }
            acc += __shfl_xor(acc, 8);
            acc += __shfl_xor(acc, 16);
            acc += __shfl_xor(acc, 32);
            float gs = acc + bs;
            float nl = (g == 2) ? ftanh(gs) : fsig(gs);

            float fv = __shfl(nl, 2 + jj, 64);
            float gv = __shfl(nl, 4 + jj, 64);
            float ov = __shfl(nl, 6 + jj, 64);

            if (lane < 2) {                   // elem lanes
                cst = fv * cst + nl * gv;
                float h = ov * ftanh(cst);
                ast(&ys2[(size_t)t * HDIM + elem], h);
                if (t == NB - 1) {
                    out[1024 + HDIM + elem] = h;     // hn L1
                    out[1536 + HDIM + elem] = cst;   // cn L1
                }
            }
        }
    }
}

// ---------------------------------------------------------------------------
// Kernel 4: fc head
// ---------------------------------------------------------------------------
__global__ __launch_bounds__(256) void fc_kernel(const float* __restrict__ ys2,
                                                 const float* __restrict__ fc_w,
                                                 const float* __restrict__ fc_b,
                                                 float* __restrict__ out) {
    const int row  = blockIdx.x * 4 + (threadIdx.x >> 6);
    const int lane = threadIdx.x & 63;
    float4 y = ((const float4*)(ys2 + (size_t)row * HDIM))[lane];
    float4 wv = ((const float4*)fc_w)[lane];
    float d = y.x * wv.x + y.y * wv.y + y.z * wv.z + y.w * wv.w;
    #pragma unroll
    for (int m = 1; m < 64; m <<= 1) d += __shfl_xor(d, m);
    if (lane == 0) out[row] = 1.f / (1.f + expf(-(d + fc_b[0])));
}

// ---------------------------------------------------------------------------
extern "C" void kernel_launch(void* const* d_in, const int* in_sizes, int n_in,
                              void* d_out, int out_size, void* d_ws, size_t ws_size,
                              hipStream_t stream) {
    const int*   x     = (const int*)  d_in[0];
    const float* h0    = (const float*)d_in[1];
    const float* c0    = (const float*)d_in[2];
    const float* emb   = (const float*)d_in[3];
    const float* w_ih0 = (const float*)d_in[4];
    const float* w_hh0 = (const float*)d_in[5];
    const float* b_ih0 = (const float*)d_in[6];
    const float* b_hh0 = (const float*)d_in[7];
    const float* w_ih1 = (const float*)d_in[8];
    const float* w_hh1 = (const float*)d_in[9];
    const float* b_ih1 = (const float*)d_in[10];
    const float* b_hh1 = (const float*)d_in[11];
    const float* fc_w  = (const float*)d_in[12];
    const float* fc_b  = (const float*)d_in[13];
    float* out = (float*)d_out;

    // workspace layout (floats)
    float* X   = (float*)d_ws;                  // 1024*903
    float* G1  = X + (size_t)NB * DIN;          // 1024*1024
    float* ys1 = G1 + (size_t)NB * GDIM;        // 1024*256
    float* ys2 = ys1 + (size_t)NB * HDIM;       // 1024*256

    // sentinel-fill both exchange buffers (0xFFFFFFFF = NaN, never produced)
    hipMemsetAsync(ys1, 0xFF, 2 * (size_t)NB * HDIM * sizeof(float), stream);

    conv_kernel<<<NB, 256, 0, stream>>>(x, emb, X);

    gemm_bias<<<dim3(16, 16), 256, 0, stream>>>(X, w_ih0, b_ih0, b_hh0, G1, DIN);

    lstm_fused<<<24, 640, 0, stream>>>(G1, w_hh0, w_ih1, w_hh1, b_ih1, b_hh1,
                                       h0, c0, ys1, ys2, out);

    fc_kernel<<<NB / 4, 256, 0, stream>>>(ys2, fc_w, fc_b, out);
}